// Round 1
// baseline (608.359 us; speedup 1.0000x reference)
//
#include <hip/hip_runtime.h>
#include <stdint.h>

typedef unsigned short u16;
typedef unsigned int   u32;
typedef __bf16 bf16_t;
typedef bf16_t bf16x8 __attribute__((ext_vector_type(8)));   // if compile fails: switch bf16_t to short
typedef u16    u16x8  __attribute__((ext_vector_type(8)));
typedef float  f32x4  __attribute__((ext_vector_type(4)));

#define NB   2
#define NL   2048
#define ND   2048
#define NHQ  32
#define NHKV 8
#define NHD  64
#define NQKV 3072   // D + 2*HKV*HD

__device__ __forceinline__ u16 f2bf(float x){
  union{float f;u32 u;} v; v.f = x;
  u32 r = v.u + 0x7FFFu + ((v.u >> 16) & 1u);   // RTNE
  return (u16)(r >> 16);
}
__device__ __forceinline__ float bf2f(u16 b){
  union{u32 u;float f;} v; v.u = ((u32)b) << 16; return v.f;
}

__device__ __forceinline__ void gload_lds16(const void* g, void* l){
  auto gp = reinterpret_cast<__attribute__((address_space(1))) u16*>(
      (uintptr_t)g);
  auto lp = reinterpret_cast<__attribute__((address_space(3))) u16*>(
      (uintptr_t)l);
  __builtin_amdgcn_global_load_lds(gp, lp, 16, 0, 0);
}

__device__ __forceinline__ f32x4 mfma16(bf16x8 a, bf16x8 b, f32x4 c){
  return __builtin_amdgcn_mfma_f32_16x16x32_bf16(a, b, c, 0, 0, 0);
}

// ---------------- fp32 -> bf16 convert (vectorized) ----------------
__global__ void k_cvt(const float* __restrict__ in, u16* __restrict__ out, int n4){
  int i = blockIdx.x * blockDim.x + threadIdx.x;
  if (i >= n4) return;
  float4 f = reinterpret_cast<const float4*>(in)[i];
  ushort4 o;
  o.x = f2bf(f.x); o.y = f2bf(f.y); o.z = f2bf(f.z); o.w = f2bf(f.w);
  reinterpret_cast<ushort4*>(out)[i] = o;
}

// ---------------- RoPE cos/sin table [L][32] ----------------
__global__ void k_rope_tab(const int* __restrict__ pos, float* __restrict__ cosT,
                           float* __restrict__ sinT){
  int idx = blockIdx.x * 256 + threadIdx.x;      // 65536 total
  int l = idx >> 5, i = idx & 31;
  float p = (float)pos[l];
  float inv = __expf(-((float)i * (1.0f/32.0f)) * 9.210340371976184f); // ln(1e4)
  float fr = p * inv;
  cosT[idx] = cosf(fr);
  sinT[idx] = sinf(fr);
}

// ---------------- bf16 NT GEMM: C[M][N] = A[M][K] * B[N][K]^T ----------------
// 128x128 tile, BK=32, 4 waves of 64x64, mfma 16x16x32, global_load_lds staging.
template<int WRITE_F32>
__global__ __launch_bounds__(256) void k_gemm_nt(const u16* __restrict__ A,
                                                 const u16* __restrict__ Bm,
                                                 void* __restrict__ Cp,
                                                 int M, int N, int K){
  __shared__ u16 As[128*32];
  __shared__ u16 Bs[128*32];
  const int tid = threadIdx.x;
  const int lane = tid & 63;
  const int w = tid >> 6;
  const int wr = w >> 1, wc = w & 1;
  const int tm = blockIdx.y * 128, tn = blockIdx.x * 128;
  const int lr = lane & 15, lg = lane >> 4;

  const int ca = 2*w, cb = 2*w+1;                 // staging chunks (16 rows each)
  const u16* pa0 = A  + (size_t)(tm + ca*16 + (lane>>2))*K + (lane&3)*8;
  const u16* pa1 = A  + (size_t)(tm + cb*16 + (lane>>2))*K + (lane&3)*8;
  const u16* pb0 = Bm + (size_t)(tn + ca*16 + (lane>>2))*K + (lane&3)*8;
  const u16* pb1 = Bm + (size_t)(tn + cb*16 + (lane>>2))*K + (lane&3)*8;
  u16* la0 = &As[ca*512];
  u16* la1 = &As[cb*512];
  u16* lb0 = &Bs[ca*512];
  u16* lb1 = &Bs[cb*512];

  f32x4 acc[4][4] = {};

  const int nk = K >> 5;
  for (int kt = 0; kt < nk; ++kt){
    gload_lds16(pa0, la0);
    gload_lds16(pa1, la1);
    gload_lds16(pb0, lb0);
    gload_lds16(pb1, lb1);
    pa0 += 32; pa1 += 32; pb0 += 32; pb1 += 32;
    __syncthreads();                              // drains vmcnt for gload_lds
    bf16x8 af[4], bfr[4];
#pragma unroll
    for (int m = 0; m < 4; ++m)
      af[m] = *reinterpret_cast<const bf16x8*>(&As[(wr*64 + m*16 + lr)*32 + lg*8]);
#pragma unroll
    for (int n = 0; n < 4; ++n)
      bfr[n] = *reinterpret_cast<const bf16x8*>(&Bs[(wc*64 + n*16 + lr)*32 + lg*8]);
#pragma unroll
    for (int m = 0; m < 4; ++m)
#pragma unroll
      for (int n = 0; n < 4; ++n)
        acc[m][n] = mfma16(af[m], bfr[n], acc[m][n]);
    __syncthreads();
  }

  // C/D layout (verified): col = lane&15, row = (lane>>4)*4 + reg
  const int rbase = tm + wr*64 + lg*4;
  const int cbase = tn + wc*64 + lr;
#pragma unroll
  for (int m = 0; m < 4; ++m){
#pragma unroll
    for (int n = 0; n < 4; ++n){
#pragma unroll
      for (int r = 0; r < 4; ++r){
        size_t off = (size_t)(rbase + m*16 + r)*N + (cbase + n*16);
        if (WRITE_F32) ((float*)Cp)[off] = acc[m][n][r];
        else           ((u16*)Cp)[off]   = f2bf(acc[m][n][r]);
      }
    }
  }
}

// ---------------- RoPE + scatter qkv -> Q[b][h][l][d], K[b][kvh][l][d], V[b][kvh][l][d]
// q additionally pre-scaled by 1/sqrt(64) = 0.125
__global__ void k_rope_scatter(const u16* __restrict__ qkv, const float* __restrict__ cosT,
                               const float* __restrict__ sinT,
                               u16* __restrict__ Q, u16* __restrict__ Ko, u16* __restrict__ V){
  const int row = blockIdx.x;                 // b*L + l
  const int b = row >> 11, l = row & 2047;
  const int t = threadIdx.x;
#pragma unroll
  for (int it = 0; it < 6; ++it){
    int pp = t + it*256;                      // pair index within the 3072-wide row
    u32 xin = *reinterpret_cast<const u32*>(&qkv[(size_t)row*NQKV + pp*2]);
    float x1 = bf2f((u16)(xin & 0xFFFFu));
    float x2 = bf2f((u16)(xin >> 16));
    if (pp < 1280){
      int i = pp & 31;
      float c = cosT[l*32 + i], s = sinT[l*32 + i];
      float y1 = x1*c - x2*s;
      float y2 = x1*s + x2*c;
      if (pp < 1024){                         // q
        int hh = pp >> 5, d = (pp & 31)*2;
        u32 o = (u32)f2bf(y1*0.125f) | ((u32)f2bf(y2*0.125f) << 16);
        *reinterpret_cast<u32*>(&Q[(((size_t)(b*NHQ + hh))*NL + l)*NHD + d]) = o;
      } else {                                // k
        int idx = pp - 1024, kvh = idx >> 5, d = (idx & 31)*2;
        u32 o = (u32)f2bf(y1) | ((u32)f2bf(y2) << 16);
        *reinterpret_cast<u32*>(&Ko[(((size_t)(b*NHKV + kvh))*NL + l)*NHD + d]) = o;
      }
    } else {                                  // v passthrough
      int idx = pp - 1280, kvh = idx >> 5, d = (idx & 31)*2;
      *reinterpret_cast<u32*>(&V[(((size_t)(b*NHKV + kvh))*NL + l)*NHD + d]) = xin;
    }
  }
}

// ---------------- V[b][kvh][l][d] -> VT[b][kvh][d][l] (LDS-tiled 64x64) ----------------
__global__ __launch_bounds__(256) void k_transpose(const u16* __restrict__ V, u16* __restrict__ VT){
  __shared__ u16 T[64*72];
  const int bid = blockIdx.x;
  const int slice = bid >> 5, tile = bid & 31;
  const u16* src = V  + (size_t)slice*NL*NHD + (size_t)tile*64*NHD;
  u16*       dst = VT + (size_t)slice*NHD*NL + (size_t)tile*64;
  const int t = threadIdx.x;
  {
    int r = t >> 2, c0 = (t & 3)*16;
    const u16x8* s = reinterpret_cast<const u16x8*>(src + (size_t)r*NHD + c0);
    *reinterpret_cast<u16x8*>(&T[r*72 + c0])     = s[0];
    *reinterpret_cast<u16x8*>(&T[r*72 + c0 + 8]) = s[1];
  }
  __syncthreads();
  {
    int d = t >> 2, l0 = (t & 3)*16;
    u16x8 v0, v1;
#pragma unroll
    for (int j = 0; j < 8; ++j) v0[j] = T[(l0+j)*72 + d];
#pragma unroll
    for (int j = 0; j < 8; ++j) v1[j] = T[(l0+8+j)*72 + d];
    u16* dp = dst + (size_t)d*NL + l0;
    *reinterpret_cast<u16x8*>(dp)     = v0;
    *reinterpret_cast<u16x8*>(dp + 8) = v1;
  }
}

// ---------------- causal GQA flash attention ----------------
// 1 wave per 16-row q-tile; KV tile = 32; 4 waves/block share (b,h); O = [b][l][h*64+d]
__global__ __launch_bounds__(256) void k_attn(const u16* __restrict__ Q, const u16* __restrict__ Kg,
                                              const u16* __restrict__ VT, u16* __restrict__ O){
  __shared__ u16 P[4*16*48];                   // per-wave P tile, stride 48 (16B-aligned rows)
  const int tid = threadIdx.x, lane = tid & 63, w = tid >> 6;
  const int lr = lane & 15, lg = lane >> 4;
  const int bid = blockIdx.x;
  const int qtg = bid & 31, h = (bid >> 5) & 31, b = bid >> 10;
  const int qt = qtg*4 + w, qbase = qt*16;
  const int kvh = h >> 2;                      // GQA group of 4
  const u16* Qp = Q  + ((size_t)(b*NHQ  + h  ))*NL*NHD;
  const u16* Kp = Kg + ((size_t)(b*NHKV + kvh))*NL*NHD;
  const u16* Vp = VT + ((size_t)(b*NHKV + kvh))*NHD*NL;
  u16* Pw = &P[w*16*48];

  // A-frag layout: lane holds row=lane&15, k=(lane>>4)*8 + 0..7
  bf16x8 aq0 = *reinterpret_cast<const bf16x8*>(&Qp[(size_t)(qbase+lr)*NHD + lg*8]);
  bf16x8 aq1 = *reinterpret_cast<const bf16x8*>(&Qp[(size_t)(qbase+lr)*NHD + 32 + lg*8]);

  f32x4 o0 = {}, o1 = {}, o2 = {}, o3 = {};
  float m[4], lsum[4];
#pragma unroll
  for (int r = 0; r < 4; ++r){ m[r] = -1e30f; lsum[r] = 0.0f; }

  const int ntiles = (qbase + 47) >> 5;
  for (int jt = 0; jt < ntiles; ++jt){
    const int kvb = jt << 5;
    f32x4 s0 = {}, s1 = {};
    {
      bf16x8 bk0 = *reinterpret_cast<const bf16x8*>(&Kp[(size_t)(kvb+lr)*NHD + lg*8]);
      bf16x8 bk1 = *reinterpret_cast<const bf16x8*>(&Kp[(size_t)(kvb+lr)*NHD + 32 + lg*8]);
      bf16x8 bk2 = *reinterpret_cast<const bf16x8*>(&Kp[(size_t)(kvb+16+lr)*NHD + lg*8]);
      bf16x8 bk3 = *reinterpret_cast<const bf16x8*>(&Kp[(size_t)(kvb+16+lr)*NHD + 32 + lg*8]);
      s0 = mfma16(aq0, bk0, s0); s0 = mfma16(aq1, bk1, s0);
      s1 = mfma16(aq0, bk2, s1); s1 = mfma16(aq1, bk3, s1);
    }
    if (kvb + 31 > qbase){                     // causal mask (only edge tiles)
#pragma unroll
      for (int r = 0; r < 4; ++r){
        int q = qbase + lg*4 + r;
        if (kvb + lr > q)      s0[r] = -1e30f;
        if (kvb + 16 + lr > q) s1[r] = -1e30f;
      }
    }
    float p0[4], p1[4], cc[4];
#pragma unroll
    for (int r = 0; r < 4; ++r){
      float t = fmaxf(s0[r], s1[r]);
      t = fmaxf(t, __shfl_xor(t, 1));
      t = fmaxf(t, __shfl_xor(t, 2));
      t = fmaxf(t, __shfl_xor(t, 4));
      t = fmaxf(t, __shfl_xor(t, 8));
      float mn = fmaxf(m[r], t);
      cc[r] = __expf(m[r] - mn);
      m[r] = mn;
      p0[r] = __expf(s0[r] - mn);
      p1[r] = __expf(s1[r] - mn);
      float rs = p0[r] + p1[r];
      rs += __shfl_xor(rs, 1);
      rs += __shfl_xor(rs, 2);
      rs += __shfl_xor(rs, 4);
      rs += __shfl_xor(rs, 8);
      lsum[r] = lsum[r]*cc[r] + rs;
    }
#pragma unroll
    for (int r = 0; r < 4; ++r){ o0[r]*=cc[r]; o1[r]*=cc[r]; o2[r]*=cc[r]; o3[r]*=cc[r]; }
    // P round-trip through LDS: C-layout -> A-fragment layout
#pragma unroll
    for (int r = 0; r < 4; ++r){
      Pw[(lg*4+r)*48 + lr]      = f2bf(p0[r]);
      Pw[(lg*4+r)*48 + 16 + lr] = f2bf(p1[r]);
    }
    asm volatile("s_waitcnt lgkmcnt(0)" ::: "memory");
    __builtin_amdgcn_sched_barrier(0);
    bf16x8 ap  = *reinterpret_cast<const bf16x8*>(&Pw[lr*48 + lg*8]);
    bf16x8 bv0 = *reinterpret_cast<const bf16x8*>(&Vp[(size_t)(     lr)*NL + kvb + lg*8]);
    bf16x8 bv1 = *reinterpret_cast<const bf16x8*>(&Vp[(size_t)(16 + lr)*NL + kvb + lg*8]);
    bf16x8 bv2 = *reinterpret_cast<const bf16x8*>(&Vp[(size_t)(32 + lr)*NL + kvb + lg*8]);
    bf16x8 bv3 = *reinterpret_cast<const bf16x8*>(&Vp[(size_t)(48 + lr)*NL + kvb + lg*8]);
    o0 = mfma16(ap, bv0, o0);
    o1 = mfma16(ap, bv1, o1);
    o2 = mfma16(ap, bv2, o2);
    o3 = mfma16(ap, bv3, o3);
  }

  u16* Op = O + ((size_t)(b*NL + qbase))*ND + h*NHD;
#pragma unroll
  for (int r = 0; r < 4; ++r){
    float inv = 1.0f / lsum[r];
    u16* rowp = Op + (size_t)(lg*4 + r)*ND;
    rowp[lr]      = f2bf(o0[r]*inv);
    rowp[16+lr]   = f2bf(o1[r]*inv);
    rowp[32+lr]   = f2bf(o2[r]*inv);
    rowp[48+lr]   = f2bf(o3[r]*inv);
  }
}

extern "C" void kernel_launch(void* const* d_in, const int* in_sizes, int n_in,
                              void* d_out, int out_size, void* d_ws, size_t ws_size,
                              hipStream_t stream){
  (void)in_sizes; (void)n_in; (void)out_size; (void)ws_size;
  const float* x   = (const float*)d_in[0];
  const int*   pos = (const int*)  d_in[1];
  const float* wq  = (const float*)d_in[2];
  const float* wk  = (const float*)d_in[3];
  const float* wv  = (const float*)d_in[4];
  const float* wo  = (const float*)d_in[5];

  char* ws = (char*)d_ws;
  size_t off = 0;
  auto alloc = [&](size_t bytes) -> void* {
    void* p = ws + off;
    off += (bytes + 255) & ~(size_t)255;
    return p;
  };
  const size_t n_x   = (size_t)NB*NL*ND;      // 8388608
  const size_t n_wq  = (size_t)ND*ND;         // 4194304
  const size_t n_wkv = (size_t)NHKV*NHD*ND;   // 1048576

  u16* xb    = (u16*)alloc(n_x*2);                       // reused later as attn output O
  u16* wqkvb = (u16*)alloc((size_t)NQKV*ND*2);
  u16* wob   = (u16*)alloc(n_wq*2);
  u16* qkv   = (u16*)alloc((size_t)NB*NL*NQKV*2);
  u16* Qb    = (u16*)alloc((size_t)NB*NHQ*NL*NHD*2);
  u16* Kb    = (u16*)alloc((size_t)NB*NHKV*NL*NHD*2);
  u16* Vb    = (u16*)alloc((size_t)NB*NHKV*NL*NHD*2);
  u16* VTb   = (u16*)alloc((size_t)NB*NHKV*NHD*NL*2);
  float* cosT= (float*)alloc((size_t)NL*32*4);
  float* sinT= (float*)alloc((size_t)NL*32*4);

  k_cvt<<<(int)(n_x/4/256),   256, 0, stream>>>(x,  xb, (int)(n_x/4));
  k_cvt<<<(int)(n_wq/4/256),  256, 0, stream>>>(wq, wqkvb, (int)(n_wq/4));
  k_cvt<<<(int)(n_wkv/4/256), 256, 0, stream>>>(wk, wqkvb + n_wq, (int)(n_wkv/4));
  k_cvt<<<(int)(n_wkv/4/256), 256, 0, stream>>>(wv, wqkvb + n_wq + n_wkv, (int)(n_wkv/4));
  k_cvt<<<(int)(n_wq/4/256),  256, 0, stream>>>(wo, wob, (int)(n_wq/4));
  k_rope_tab<<<(NL*32)/256, 256, 0, stream>>>(pos, cosT, sinT);

  k_gemm_nt<0><<<dim3(NQKV/128, (NB*NL)/128), 256, 0, stream>>>(xb, wqkvb, qkv, NB*NL, NQKV, ND);
  k_rope_scatter<<<NB*NL, 256, 0, stream>>>(qkv, cosT, sinT, Qb, Kb, Vb);
  k_transpose<<<NB*NHKV*(NL/64), 256, 0, stream>>>(Vb, VTb);
  k_attn<<<NB*NHQ*(NL/64), 256, 0, stream>>>(Qb, Kb, VTb, xb /* O overwrites xb */);
  k_gemm_nt<1><<<dim3(ND/128, (NB*NL)/128), 256, 0, stream>>>(xb, wob, d_out, NB*NL, ND, ND);
}

// Round 2
// 292.791 us; speedup vs baseline: 2.0778x; 2.0778x over previous
//
#include <hip/hip_runtime.h>
#include <stdint.h>

typedef unsigned short u16;
typedef unsigned int   u32;
typedef __bf16 bf16_t;
typedef bf16_t bf16x8 __attribute__((ext_vector_type(8)));
typedef u16    u16x8  __attribute__((ext_vector_type(8)));
typedef float  f32x4  __attribute__((ext_vector_type(4)));
typedef float  f32x16 __attribute__((ext_vector_type(16)));

#define NB   2
#define NL   2048
#define ND   2048
#define NHQ  32
#define NHKV 8
#define NHD  64
#define NQKV 3072   // D + 2*HKV*HD

__device__ __forceinline__ u16 f2bf(float x){
  union{float f;u32 u;} v; v.f = x;
  u32 r = v.u + 0x7FFFu + ((v.u >> 16) & 1u);   // RTNE
  return (u16)(r >> 16);
}
__device__ __forceinline__ float bf2f(u16 b){
  union{u32 u;float f;} v; v.u = ((u32)b) << 16; return v.f;
}

__device__ __forceinline__ void gload_lds16(const void* g, void* l){
  auto gp = reinterpret_cast<__attribute__((address_space(1))) u16*>(
      (uintptr_t)g);
  auto lp = reinterpret_cast<__attribute__((address_space(3))) u16*>(
      (uintptr_t)l);
  __builtin_amdgcn_global_load_lds(gp, lp, 16, 0, 0);
}

__device__ __forceinline__ f32x4 mfma16(bf16x8 a, bf16x8 b, f32x4 c){
  return __builtin_amdgcn_mfma_f32_16x16x32_bf16(a, b, c, 0, 0, 0);
}
__device__ __forceinline__ f32x16 mfma32(bf16x8 a, bf16x8 b, f32x16 c){
  return __builtin_amdgcn_mfma_f32_32x32x16_bf16(a, b, c, 0, 0, 0);
}
__device__ __forceinline__ u32 cvtpk(float lo, float hi){
  u32 w;
  asm("v_cvt_pk_bf16_f32 %0, %1, %2" : "=v"(w) : "v"(lo), "v"(hi));
  return w;
}

// ---------------- fp32 -> bf16 convert (vectorized) ----------------
__global__ void k_cvt(const float* __restrict__ in, u16* __restrict__ out, int n4){
  int i = blockIdx.x * blockDim.x + threadIdx.x;
  if (i >= n4) return;
  float4 f = reinterpret_cast<const float4*>(in)[i];
  ushort4 o;
  o.x = f2bf(f.x); o.y = f2bf(f.y); o.z = f2bf(f.z); o.w = f2bf(f.w);
  reinterpret_cast<ushort4*>(out)[i] = o;
}

// ---------------- RoPE cos/sin table [L][32] ----------------
__global__ void k_rope_tab(const int* __restrict__ pos, float* __restrict__ cosT,
                           float* __restrict__ sinT){
  int idx = blockIdx.x * 256 + threadIdx.x;      // 65536 total
  int l = idx >> 5, i = idx & 31;
  float p = (float)pos[l];
  float inv = __expf(-((float)i * (1.0f/32.0f)) * 9.210340371976184f); // ln(1e4)
  float fr = p * inv;
  cosT[idx] = cosf(fr);
  sinT[idx] = sinf(fr);
}

// ---------------- bf16 NT GEMM: C[M][N] = A[M][K] * B[N][K]^T ----------------
template<int WRITE_F32>
__global__ __launch_bounds__(256) void k_gemm_nt(const u16* __restrict__ A,
                                                 const u16* __restrict__ Bm,
                                                 void* __restrict__ Cp,
                                                 int M, int N, int K){
  __shared__ u16 As[128*32];
  __shared__ u16 Bs[128*32];
  const int tid = threadIdx.x;
  const int lane = tid & 63;
  const int w = tid >> 6;
  const int wr = w >> 1, wc = w & 1;
  const int tm = blockIdx.y * 128, tn = blockIdx.x * 128;
  const int lr = lane & 15, lg = lane >> 4;

  const int ca = 2*w, cb = 2*w+1;
  const u16* pa0 = A  + (size_t)(tm + ca*16 + (lane>>2))*K + (lane&3)*8;
  const u16* pa1 = A  + (size_t)(tm + cb*16 + (lane>>2))*K + (lane&3)*8;
  const u16* pb0 = Bm + (size_t)(tn + ca*16 + (lane>>2))*K + (lane&3)*8;
  const u16* pb1 = Bm + (size_t)(tn + cb*16 + (lane>>2))*K + (lane&3)*8;
  u16* la0 = &As[ca*512];
  u16* la1 = &As[cb*512];
  u16* lb0 = &Bs[ca*512];
  u16* lb1 = &Bs[cb*512];

  f32x4 acc[4][4] = {};

  const int nk = K >> 5;
  for (int kt = 0; kt < nk; ++kt){
    gload_lds16(pa0, la0);
    gload_lds16(pa1, la1);
    gload_lds16(pb0, lb0);
    gload_lds16(pb1, lb1);
    pa0 += 32; pa1 += 32; pb0 += 32; pb1 += 32;
    __syncthreads();
    bf16x8 af[4], bfr[4];
#pragma unroll
    for (int m = 0; m < 4; ++m)
      af[m] = *reinterpret_cast<const bf16x8*>(&As[(wr*64 + m*16 + lr)*32 + lg*8]);
#pragma unroll
    for (int n = 0; n < 4; ++n)
      bfr[n] = *reinterpret_cast<const bf16x8*>(&Bs[(wc*64 + n*16 + lr)*32 + lg*8]);
#pragma unroll
    for (int m = 0; m < 4; ++m)
#pragma unroll
      for (int n = 0; n < 4; ++n)
        acc[m][n] = mfma16(af[m], bfr[n], acc[m][n]);
    __syncthreads();
  }

  const int rbase = tm + wr*64 + lg*4;
  const int cbase = tn + wc*64 + lr;
#pragma unroll
  for (int m = 0; m < 4; ++m){
#pragma unroll
    for (int n = 0; n < 4; ++n){
#pragma unroll
      for (int r = 0; r < 4; ++r){
        size_t off = (size_t)(rbase + m*16 + r)*N + (cbase + n*16);
        if (WRITE_F32) ((float*)Cp)[off] = acc[m][n][r];
        else           ((u16*)Cp)[off]   = f2bf(acc[m][n][r]);
      }
    }
  }
}

// ---------------- RoPE + scatter ----------------
__global__ void k_rope_scatter(const u16* __restrict__ qkv, const float* __restrict__ cosT,
                               const float* __restrict__ sinT,
                               u16* __restrict__ Q, u16* __restrict__ Ko, u16* __restrict__ V){
  const int row = blockIdx.x;                 // b*L + l
  const int b = row >> 11, l = row & 2047;
  const int t = threadIdx.x;
#pragma unroll
  for (int it = 0; it < 6; ++it){
    int pp = t + it*256;
    u32 xin = *reinterpret_cast<const u32*>(&qkv[(size_t)row*NQKV + pp*2]);
    float x1 = bf2f((u16)(xin & 0xFFFFu));
    float x2 = bf2f((u16)(xin >> 16));
    if (pp < 1280){
      int i = pp & 31;
      float c = cosT[l*32 + i], s = sinT[l*32 + i];
      float y1 = x1*c - x2*s;
      float y2 = x1*s + x2*c;
      if (pp < 1024){
        int hh = pp >> 5, d = (pp & 31)*2;
        u32 o = (u32)f2bf(y1*0.125f) | ((u32)f2bf(y2*0.125f) << 16);
        *reinterpret_cast<u32*>(&Q[(((size_t)(b*NHQ + hh))*NL + l)*NHD + d]) = o;
      } else {
        int idx = pp - 1024, kvh = idx >> 5, d = (idx & 31)*2;
        u32 o = (u32)f2bf(y1) | ((u32)f2bf(y2) << 16);
        *reinterpret_cast<u32*>(&Ko[(((size_t)(b*NHKV + kvh))*NL + l)*NHD + d]) = o;
      }
    } else {
      int idx = pp - 1280, kvh = idx >> 5, d = (idx & 31)*2;
      *reinterpret_cast<u32*>(&V[(((size_t)(b*NHKV + kvh))*NL + l)*NHD + d]) = xin;
    }
  }
}

// ---------------- V[b][kvh][l][d] -> VT[b][kvh][d][l] ----------------
__global__ __launch_bounds__(256) void k_transpose(const u16* __restrict__ V, u16* __restrict__ VT){
  __shared__ u16 T[64*72];
  const int bid = blockIdx.x;
  const int slice = bid >> 5, tile = bid & 31;
  const u16* src = V  + (size_t)slice*NL*NHD + (size_t)tile*64*NHD;
  u16*       dst = VT + (size_t)slice*NHD*NL + (size_t)tile*64;
  const int t = threadIdx.x;
  {
    int r = t >> 2, c0 = (t & 3)*16;
    const u16x8* s = reinterpret_cast<const u16x8*>(src + (size_t)r*NHD + c0);
    *reinterpret_cast<u16x8*>(&T[r*72 + c0])     = s[0];
    *reinterpret_cast<u16x8*>(&T[r*72 + c0 + 8]) = s[1];
  }
  __syncthreads();
  {
    int d = t >> 2, l0 = (t & 3)*16;
    u16x8 v0, v1;
#pragma unroll
    for (int j = 0; j < 8; ++j) v0[j] = T[(l0+j)*72 + d];
#pragma unroll
    for (int j = 0; j < 8; ++j) v1[j] = T[(l0+8+j)*72 + d];
    u16* dp = dst + (size_t)d*NL + l0;
    *reinterpret_cast<u16x8*>(dp)     = v0;
    *reinterpret_cast<u16x8*>(dp + 8) = v1;
  }
}

// ---------------- causal GQA flash attention, swapped 32x32 MFMA ----------------
// 1 wave = 32 q rows (one q-tile). Wave processes q-tile pair (t, 63-t) for
// causal balance. S^T = mfma32(K, Q): lane holds q = lane&31, 32 k values.
// Softmax fully in-register (1 shfl_xor(32) per reduce). P -> bf16 A-frags via
// v_cvt_pk_bf16_f32 + v_permlane32_swap_b32. PV computes O^T = V^T * P^T so
// the lane again owns one q row; 1/l is a per-lane scalar.
__global__ __launch_bounds__(256) void k_attn2(const u16* __restrict__ Q, const u16* __restrict__ Kg,
                                               const u16* __restrict__ VT, u16* __restrict__ O){
  const int tid = threadIdx.x, lane = tid & 63, w = tid >> 6;
  const int q32 = lane & 31, hi = lane >> 5;
  const int task = blockIdx.x * 4 + w;          // 2048 wave-tasks
  const int pr = task & 31, h = (task >> 5) & 31, b = task >> 10;
  const int kvh = h >> 2;
  const u16* Qp = Q  + ((size_t)(b*NHQ  + h  ))*NL*NHD;
  const u16* Kp = Kg + ((size_t)(b*NHKV + kvh))*NL*NHD;
  const u16* Vp = VT + ((size_t)(b*NHKV + kvh))*NHD*NL;

#pragma unroll 1
  for (int sel = 0; sel < 2; ++sel){
    const int qt = sel ? (63 - pr) : pr;
    const int qbase = qt * 32;
    const int qrow = qbase + q32;

    bf16x8 qf[4];
#pragma unroll
    for (int ks = 0; ks < 4; ++ks)
      qf[ks] = *reinterpret_cast<const bf16x8*>(&Qp[(size_t)qrow*NHD + ks*16 + hi*8]);

    f32x16 o0 = {}, o1 = {};
    float mrun = -1e30f, lsum = 0.0f;
    const int ntiles = (qbase + 95) >> 6;

    for (int jt = 0; jt < ntiles; ++jt){
      const int kvb = jt << 6;
      // ---- S^T = K . Q^T  (2 m-tiles of 32 k, 4 k-steps over d=64) ----
      f32x16 s0 = {}, s1 = {};
#pragma unroll
      for (int ks = 0; ks < 4; ++ks){
        bf16x8 kf0 = *reinterpret_cast<const bf16x8*>(&Kp[(size_t)(kvb + q32)*NHD + ks*16 + hi*8]);
        bf16x8 kf1 = *reinterpret_cast<const bf16x8*>(&Kp[(size_t)(kvb + 32 + q32)*NHD + ks*16 + hi*8]);
        s0 = mfma32(kf0, qf[ks], s0);
        s1 = mfma32(kf1, qf[ks], s1);
      }
      float pv[32];
#pragma unroll
      for (int r = 0; r < 16; ++r){ pv[r] = s0[r]; pv[16+r] = s1[r]; }
      if (jt == ntiles-1){                        // causal mask, edge tile only
#pragma unroll
        for (int r = 0; r < 16; ++r){
          const int kl = (r&3) + 8*(r>>2) + 4*hi; // C-layout row for reg r
          pv[r]      = (kvb + kl      <= qrow) ? pv[r]      : -1e30f;
          pv[16+r]   = (kvb + 32 + kl <= qrow) ? pv[16+r]   : -1e30f;
        }
      }
      // ---- row max: in-register tree + one cross-half shuffle ----
      float t[16];
#pragma unroll
      for (int r = 0; r < 16; ++r) t[r] = fmaxf(pv[r], pv[16+r]);
#pragma unroll
      for (int r = 0; r < 8; ++r)  t[r] = fmaxf(t[r], t[r+8]);
#pragma unroll
      for (int r = 0; r < 4; ++r)  t[r] = fmaxf(t[r], t[r+4]);
      t[0] = fmaxf(fmaxf(t[0], t[1]), fmaxf(t[2], t[3]));
      const float mnew = fmaxf(t[0], __shfl_xor(t[0], 32));
      // ---- defer-max rescale (T13, THR=8) ----
      if (__any(mnew - mrun > 8.0f)){
        const float mupd = fmaxf(mrun, mnew);
        const float c = __expf(mrun - mupd);
        lsum *= c;
#pragma unroll
        for (int r = 0; r < 16; ++r){ o0[r] *= c; o1[r] *= c; }
        mrun = mupd;
      }
      // ---- P = exp(S - m), row-sum ----
      float p[32];
#pragma unroll
      for (int r = 0; r < 32; ++r) p[r] = __expf(pv[r] - mrun);
      float u[16];
#pragma unroll
      for (int r = 0; r < 16; ++r) u[r] = p[r] + p[16+r];
#pragma unroll
      for (int r = 0; r < 8; ++r)  u[r] += u[r+8];
#pragma unroll
      for (int r = 0; r < 4; ++r)  u[r] += u[r+4];
      lsum += (u[0]+u[1]) + (u[2]+u[3]);
      // ---- P -> bf16 B-frags (cvt_pk + permlane32_swap, in-register) ----
      u32 wds[16];
#pragma unroll
      for (int i = 0; i < 16; ++i) wds[i] = cvtpk(p[2*i], p[2*i+1]);
      bf16x8 pf[4];
#pragma unroll
      for (int f = 0; f < 4; ++f){
        u32 x  = wds[4*f+0], y  = wds[4*f+2];
        u32 x2 = wds[4*f+1], y2 = wds[4*f+3];
        asm("v_permlane32_swap_b32 %0, %1" : "+v"(x),  "+v"(y));
        asm("v_permlane32_swap_b32 %0, %1" : "+v"(x2), "+v"(y2));
        union { u32 wq[4]; bf16x8 v; } uu;
        uu.wq[0] = x; uu.wq[1] = x2; uu.wq[2] = y; uu.wq[3] = y2;
        pf[f] = uu.v;
      }
      // ---- O^T += V^T . P^T  (2 d-tiles, 4 k-steps over 64 k) ----
#pragma unroll
      for (int ks = 0; ks < 4; ++ks){
        bf16x8 vf0 = *reinterpret_cast<const bf16x8*>(&Vp[(size_t)(q32)*NL      + kvb + ks*16 + hi*8]);
        bf16x8 vf1 = *reinterpret_cast<const bf16x8*>(&Vp[(size_t)(32 + q32)*NL + kvb + ks*16 + hi*8]);
        o0 = mfma32(vf0, pf[ks], o0);
        o1 = mfma32(vf1, pf[ks], o1);
      }
    }

    lsum += __shfl_xor(lsum, 32);
    const float inv = 1.0f / lsum;
    u16* Op = O + ((size_t)(b*NL + qrow))*ND + h*NHD;
#pragma unroll
    for (int md = 0; md < 2; ++md){
#pragma unroll
      for (int q4 = 0; q4 < 4; ++q4){
        ushort4 st;
        float a0 = (md ? o1[4*q4+0] : o0[4*q4+0]) * inv;
        float a1 = (md ? o1[4*q4+1] : o0[4*q4+1]) * inv;
        float a2 = (md ? o1[4*q4+2] : o0[4*q4+2]) * inv;
        float a3 = (md ? o1[4*q4+3] : o0[4*q4+3]) * inv;
        st.x = f2bf(a0); st.y = f2bf(a1); st.z = f2bf(a2); st.w = f2bf(a3);
        *reinterpret_cast<ushort4*>(&Op[md*32 + 8*q4 + 4*hi]) = st;
      }
    }
  }
}

extern "C" void kernel_launch(void* const* d_in, const int* in_sizes, int n_in,
                              void* d_out, int out_size, void* d_ws, size_t ws_size,
                              hipStream_t stream){
  (void)in_sizes; (void)n_in; (void)out_size; (void)ws_size;
  const float* x   = (const float*)d_in[0];
  const int*   pos = (const int*)  d_in[1];
  const float* wq  = (const float*)d_in[2];
  const float* wk  = (const float*)d_in[3];
  const float* wv  = (const float*)d_in[4];
  const float* wo  = (const float*)d_in[5];

  char* ws = (char*)d_ws;
  size_t off = 0;
  auto alloc = [&](size_t bytes) -> void* {
    void* p = ws + off;
    off += (bytes + 255) & ~(size_t)255;
    return p;
  };
  const size_t n_x   = (size_t)NB*NL*ND;
  const size_t n_wq  = (size_t)ND*ND;
  const size_t n_wkv = (size_t)NHKV*NHD*ND;

  u16* xb    = (u16*)alloc(n_x*2);                       // reused as attn output O
  u16* wqkvb = (u16*)alloc((size_t)NQKV*ND*2);
  u16* wob   = (u16*)alloc(n_wq*2);
  u16* qkv   = (u16*)alloc((size_t)NB*NL*NQKV*2);
  u16* Qb    = (u16*)alloc((size_t)NB*NHQ*NL*NHD*2);
  u16* Kb    = (u16*)alloc((size_t)NB*NHKV*NL*NHD*2);
  u16* Vb    = (u16*)alloc((size_t)NB*NHKV*NL*NHD*2);
  u16* VTb   = (u16*)alloc((size_t)NB*NHKV*NHD*NL*2);
  float* cosT= (float*)alloc((size_t)NL*32*4);
  float* sinT= (float*)alloc((size_t)NL*32*4);

  k_cvt<<<(int)(n_x/4/256),   256, 0, stream>>>(x,  xb, (int)(n_x/4));
  k_cvt<<<(int)(n_wq/4/256),  256, 0, stream>>>(wq, wqkvb, (int)(n_wq/4));
  k_cvt<<<(int)(n_wkv/4/256), 256, 0, stream>>>(wk, wqkvb + n_wq, (int)(n_wkv/4));
  k_cvt<<<(int)(n_wkv/4/256), 256, 0, stream>>>(wv, wqkvb + n_wq + n_wkv, (int)(n_wkv/4));
  k_cvt<<<(int)(n_wq/4/256),  256, 0, stream>>>(wo, wob, (int)(n_wq/4));
  k_rope_tab<<<(NL*32)/256, 256, 0, stream>>>(pos, cosT, sinT);

  k_gemm_nt<0><<<dim3(NQKV/128, (NB*NL)/128), 256, 0, stream>>>(xb, wqkvb, qkv, NB*NL, NQKV, ND);
  k_rope_scatter<<<NB*NL, 256, 0, stream>>>(qkv, cosT, sinT, Qb, Kb, Vb);
  k_transpose<<<NB*NHKV*(NL/64), 256, 0, stream>>>(Vb, VTb);
  k_attn2<<<512, 256, 0, stream>>>(Qb, Kb, VTb, xb);
  k_gemm_nt<1><<<dim3(ND/128, (NB*NL)/128), 256, 0, stream>>>(xb, wob, d_out, NB*NL, ND, ND);
}

// Round 3
// 283.761 us; speedup vs baseline: 2.1439x; 1.0318x over previous
//
#include <hip/hip_runtime.h>
#include <stdint.h>

typedef unsigned short u16;
typedef unsigned int   u32;
typedef __bf16 bf16_t;
typedef bf16_t bf16x8 __attribute__((ext_vector_type(8)));
typedef u16    u16x8  __attribute__((ext_vector_type(8)));
typedef float  f32x4  __attribute__((ext_vector_type(4)));
typedef float  f32x16 __attribute__((ext_vector_type(16)));

#define NB   2
#define NL   2048
#define ND   2048
#define NHQ  32
#define NHKV 8
#define NHD  64
#define NQKV 3072   // D + 2*HKV*HD
#define QSCALE 0.18033688011112042f   // 0.125 * log2(e): softmax runs in exp2 domain

__device__ __forceinline__ u16 f2bf(float x){
  union{float f;u32 u;} v; v.f = x;
  u32 r = v.u + 0x7FFFu + ((v.u >> 16) & 1u);   // RTNE
  return (u16)(r >> 16);
}
__device__ __forceinline__ float bf2f(u16 b){
  union{u32 u;float f;} v; v.u = ((u32)b) << 16; return v.f;
}

__device__ __forceinline__ float exp2_hw(float x){
#if __has_builtin(__builtin_amdgcn_exp2f)
  return __builtin_amdgcn_exp2f(x);
#else
  float r; asm("v_exp_f32 %0, %1" : "=v"(r) : "v"(x)); return r;
#endif
}

__device__ __forceinline__ void gload_lds16(const void* g, void* l){
  auto gp = reinterpret_cast<__attribute__((address_space(1))) u16*>(
      (uintptr_t)g);
  auto lp = reinterpret_cast<__attribute__((address_space(3))) u16*>(
      (uintptr_t)l);
  __builtin_amdgcn_global_load_lds(gp, lp, 16, 0, 0);
}

__device__ __forceinline__ f32x4 mfma16(bf16x8 a, bf16x8 b, f32x4 c){
  return __builtin_amdgcn_mfma_f32_16x16x32_bf16(a, b, c, 0, 0, 0);
}
__device__ __forceinline__ f32x16 mfma32(bf16x8 a, bf16x8 b, f32x16 c){
  return __builtin_amdgcn_mfma_f32_32x32x16_bf16(a, b, c, 0, 0, 0);
}
__device__ __forceinline__ u32 cvtpk(float lo, float hi){
  u32 w;
  asm("v_cvt_pk_bf16_f32 %0, %1, %2" : "=v"(w) : "v"(lo), "v"(hi));
  return w;
}

// ---------------- fp32 -> bf16 convert (vectorized) ----------------
__global__ void k_cvt(const float* __restrict__ in, u16* __restrict__ out, int n4){
  int i = blockIdx.x * blockDim.x + threadIdx.x;
  if (i >= n4) return;
  float4 f = reinterpret_cast<const float4*>(in)[i];
  ushort4 o;
  o.x = f2bf(f.x); o.y = f2bf(f.y); o.z = f2bf(f.z); o.w = f2bf(f.w);
  reinterpret_cast<ushort4*>(out)[i] = o;
}

// ---------------- RoPE cos/sin table [L][32] ----------------
__global__ void k_rope_tab(const int* __restrict__ pos, float* __restrict__ cosT,
                           float* __restrict__ sinT){
  int idx = blockIdx.x * 256 + threadIdx.x;      // 65536 total
  int l = idx >> 5, i = idx & 31;
  float p = (float)pos[l];
  float inv = __expf(-((float)i * (1.0f/32.0f)) * 9.210340371976184f); // ln(1e4)
  float fr = p * inv;
  cosT[idx] = cosf(fr);
  sinT[idx] = sinf(fr);
}

// ---------------- bf16 NT GEMM: C[M][N] = A[M][K] * B[N][K]^T ----------------
template<int WRITE_F32>
__global__ __launch_bounds__(256) void k_gemm_nt(const u16* __restrict__ A,
                                                 const u16* __restrict__ Bm,
                                                 void* __restrict__ Cp,
                                                 int M, int N, int K){
  __shared__ u16 As[128*32];
  __shared__ u16 Bs[128*32];
  const int tid = threadIdx.x;
  const int lane = tid & 63;
  const int w = tid >> 6;
  const int wr = w >> 1, wc = w & 1;
  const int tm = blockIdx.y * 128, tn = blockIdx.x * 128;
  const int lr = lane & 15, lg = lane >> 4;

  const int ca = 2*w, cb = 2*w+1;
  const u16* pa0 = A  + (size_t)(tm + ca*16 + (lane>>2))*K + (lane&3)*8;
  const u16* pa1 = A  + (size_t)(tm + cb*16 + (lane>>2))*K + (lane&3)*8;
  const u16* pb0 = Bm + (size_t)(tn + ca*16 + (lane>>2))*K + (lane&3)*8;
  const u16* pb1 = Bm + (size_t)(tn + cb*16 + (lane>>2))*K + (lane&3)*8;
  u16* la0 = &As[ca*512];
  u16* la1 = &As[cb*512];
  u16* lb0 = &Bs[ca*512];
  u16* lb1 = &Bs[cb*512];

  f32x4 acc[4][4] = {};

  const int nk = K >> 5;
  for (int kt = 0; kt < nk; ++kt){
    gload_lds16(pa0, la0);
    gload_lds16(pa1, la1);
    gload_lds16(pb0, lb0);
    gload_lds16(pb1, lb1);
    pa0 += 32; pa1 += 32; pb0 += 32; pb1 += 32;
    __syncthreads();
    bf16x8 af[4], bfr[4];
#pragma unroll
    for (int m = 0; m < 4; ++m)
      af[m] = *reinterpret_cast<const bf16x8*>(&As[(wr*64 + m*16 + lr)*32 + lg*8]);
#pragma unroll
    for (int n = 0; n < 4; ++n)
      bfr[n] = *reinterpret_cast<const bf16x8*>(&Bs[(wc*64 + n*16 + lr)*32 + lg*8]);
#pragma unroll
    for (int m = 0; m < 4; ++m)
#pragma unroll
      for (int n = 0; n < 4; ++n)
        acc[m][n] = mfma16(af[m], bfr[n], acc[m][n]);
    __syncthreads();
  }

  const int rbase = tm + wr*64 + lg*4;
  const int cbase = tn + wc*64 + lr;
#pragma unroll
  for (int m = 0; m < 4; ++m){
#pragma unroll
    for (int n = 0; n < 4; ++n){
#pragma unroll
      for (int r = 0; r < 4; ++r){
        size_t off = (size_t)(rbase + m*16 + r)*N + (cbase + n*16);
        if (WRITE_F32) ((float*)Cp)[off] = acc[m][n][r];
        else           ((u16*)Cp)[off]   = f2bf(acc[m][n][r]);
      }
    }
  }
}

// ---------------- RoPE + scatter ----------------
__global__ void k_rope_scatter(const u16* __restrict__ qkv, const float* __restrict__ cosT,
                               const float* __restrict__ sinT,
                               u16* __restrict__ Q, u16* __restrict__ Ko, u16* __restrict__ V){
  const int row = blockIdx.x;                 // b*L + l
  const int b = row >> 11, l = row & 2047;
  const int t = threadIdx.x;
#pragma unroll
  for (int it = 0; it < 6; ++it){
    int pp = t + it*256;
    u32 xin = *reinterpret_cast<const u32*>(&qkv[(size_t)row*NQKV + pp*2]);
    float x1 = bf2f((u16)(xin & 0xFFFFu));
    float x2 = bf2f((u16)(xin >> 16));
    if (pp < 1280){
      int i = pp & 31;
      float c = cosT[l*32 + i], s = sinT[l*32 + i];
      float y1 = x1*c - x2*s;
      float y2 = x1*s + x2*c;
      if (pp < 1024){
        int hh = pp >> 5, d = (pp & 31)*2;
        u32 o = (u32)f2bf(y1*QSCALE) | ((u32)f2bf(y2*QSCALE) << 16);
        *reinterpret_cast<u32*>(&Q[(((size_t)(b*NHQ + hh))*NL + l)*NHD + d]) = o;
      } else {
        int idx = pp - 1024, kvh = idx >> 5, d = (idx & 31)*2;
        u32 o = (u32)f2bf(y1) | ((u32)f2bf(y2) << 16);
        *reinterpret_cast<u32*>(&Ko[(((size_t)(b*NHKV + kvh))*NL + l)*NHD + d]) = o;
      }
    } else {
      int idx = pp - 1280, kvh = idx >> 5, d = (idx & 31)*2;
      *reinterpret_cast<u32*>(&V[(((size_t)(b*NHKV + kvh))*NL + l)*NHD + d]) = xin;
    }
  }
}

// ---------------- V[b][kvh][l][d] -> VT[b][kvh][d][l] ----------------
__global__ __launch_bounds__(256) void k_transpose(const u16* __restrict__ V, u16* __restrict__ VT){
  __shared__ u16 T[64*72];
  const int bid = blockIdx.x;
  const int slice = bid >> 5, tile = bid & 31;
  const u16* src = V  + (size_t)slice*NL*NHD + (size_t)tile*64*NHD;
  u16*       dst = VT + (size_t)slice*NHD*NL + (size_t)tile*64;
  const int t = threadIdx.x;
  {
    int r = t >> 2, c0 = (t & 3)*16;
    const u16x8* s = reinterpret_cast<const u16x8*>(src + (size_t)r*NHD + c0);
    *reinterpret_cast<u16x8*>(&T[r*72 + c0])     = s[0];
    *reinterpret_cast<u16x8*>(&T[r*72 + c0 + 8]) = s[1];
  }
  __syncthreads();
  {
    int d = t >> 2, l0 = (t & 3)*16;
    u16x8 v0, v1;
#pragma unroll
    for (int j = 0; j < 8; ++j) v0[j] = T[(l0+j)*72 + d];
#pragma unroll
    for (int j = 0; j < 8; ++j) v1[j] = T[(l0+8+j)*72 + d];
    u16* dp = dst + (size_t)d*NL + l0;
    *reinterpret_cast<u16x8*>(dp)     = v0;
    *reinterpret_cast<u16x8*>(dp + 8) = v1;
  }
}

// ---------------- causal GQA flash attention, dual-stream 32x32 MFMA ----------------
// A wave owns q-tiles A=pr and B=63-pr (causal balance). At the same KV step both
// streams consume the SAME K/V tile -> load frags once, run two independent
// QK/softmax/PV chains in one basic block (compiler interleaves: B's MFMA hides
// A's softmax VALU). Softmax in exp2 domain (log2e folded into Q scale).
struct AttnStream {
  f32x16 o0, o1;
  float mrun, lsum;
  bf16x8 qf[4];
  int qrow;
};

__device__ __forceinline__ void load_kfrag(bf16x8 f[8], const u16* Kp, int kvb, int q32, int hi){
#pragma unroll
  for (int ks = 0; ks < 4; ++ks){
    f[ks]   = *reinterpret_cast<const bf16x8*>(&Kp[(size_t)(kvb + q32)*NHD      + ks*16 + hi*8]);
    f[4+ks] = *reinterpret_cast<const bf16x8*>(&Kp[(size_t)(kvb + 32 + q32)*NHD + ks*16 + hi*8]);
  }
}
__device__ __forceinline__ void load_vfrag(bf16x8 f[8], const u16* Vp, int kvb, int q32, int hi){
#pragma unroll
  for (int ks = 0; ks < 4; ++ks){
    f[ks]   = *reinterpret_cast<const bf16x8*>(&Vp[(size_t)(q32)*NL      + kvb + ks*16 + hi*8]);
    f[4+ks] = *reinterpret_cast<const bf16x8*>(&Vp[(size_t)(32 + q32)*NL + kvb + ks*16 + hi*8]);
  }
}

template<bool MASK>
__device__ __forceinline__ void tile_stream(AttnStream& st, const bf16x8 kf[8], const bf16x8 vf[8],
                                            int kvb, int hi){
  f32x16 s0 = {}, s1 = {};
#pragma unroll
  for (int ks = 0; ks < 4; ++ks){
    s0 = mfma32(kf[ks],   st.qf[ks], s0);
    s1 = mfma32(kf[4+ks], st.qf[ks], s1);
  }
  float pv[32];
#pragma unroll
  for (int r = 0; r < 16; ++r){ pv[r] = s0[r]; pv[16+r] = s1[r]; }
  if (MASK){
#pragma unroll
    for (int r = 0; r < 16; ++r){
      const int kl = (r&3) + 8*(r>>2) + 4*hi;
      pv[r]    = (kvb + kl      <= st.qrow) ? pv[r]    : -1e30f;
      pv[16+r] = (kvb + 32 + kl <= st.qrow) ? pv[16+r] : -1e30f;
    }
  }
  // row max: in-register tree + one cross-half shuffle
  float t[16];
#pragma unroll
  for (int r = 0; r < 16; ++r) t[r] = fmaxf(pv[r], pv[16+r]);
#pragma unroll
  for (int r = 0; r < 8; ++r)  t[r] = fmaxf(t[r], t[r+8]);
#pragma unroll
  for (int r = 0; r < 4; ++r)  t[r] = fmaxf(t[r], t[r+4]);
  t[0] = fmaxf(fmaxf(t[0], t[1]), fmaxf(t[2], t[3]));
  const float mnew = fmaxf(t[0], __shfl_xor(t[0], 32));
  if (__any(mnew - st.mrun > 8.0f)){           // defer-max (T13)
    const float mupd = fmaxf(st.mrun, mnew);
    const float c = exp2_hw(st.mrun - mupd);
    st.lsum *= c;
#pragma unroll
    for (int r = 0; r < 16; ++r){ st.o0[r] *= c; st.o1[r] *= c; }
    st.mrun = mupd;
  }
  float p[32];
#pragma unroll
  for (int r = 0; r < 32; ++r) p[r] = exp2_hw(pv[r] - st.mrun);
  float u[16];
#pragma unroll
  for (int r = 0; r < 16; ++r) u[r] = p[r] + p[16+r];
#pragma unroll
  for (int r = 0; r < 8; ++r)  u[r] += u[r+8];
#pragma unroll
  for (int r = 0; r < 4; ++r)  u[r] += u[r+4];
  st.lsum += (u[0]+u[1]) + (u[2]+u[3]);
  // P -> bf16 B-frags (cvt_pk + permlane32_swap, in-register)
  u32 wds[16];
#pragma unroll
  for (int i = 0; i < 16; ++i) wds[i] = cvtpk(p[2*i], p[2*i+1]);
  bf16x8 pf[4];
#pragma unroll
  for (int f = 0; f < 4; ++f){
    u32 x  = wds[4*f+0], y  = wds[4*f+2];
    u32 x2 = wds[4*f+1], y2 = wds[4*f+3];
    asm("v_permlane32_swap_b32 %0, %1" : "+v"(x),  "+v"(y));
    asm("v_permlane32_swap_b32 %0, %1" : "+v"(x2), "+v"(y2));
    union { u32 wq[4]; bf16x8 v; } uu;
    uu.wq[0] = x; uu.wq[1] = x2; uu.wq[2] = y; uu.wq[3] = y2;
    pf[f] = uu.v;
  }
#pragma unroll
  for (int ks = 0; ks < 4; ++ks){
    st.o0 = mfma32(vf[ks],   pf[ks], st.o0);
    st.o1 = mfma32(vf[4+ks], pf[ks], st.o1);
  }
}

__device__ __forceinline__ void store_stream(const AttnStream& st, u16* O, int b, int h, int hi){
  float l = st.lsum + __shfl_xor(st.lsum, 32);
  const float inv = 1.0f / l;
  u16* Op = O + ((size_t)(b*NL + st.qrow))*ND + h*NHD;
#pragma unroll
  for (int md = 0; md < 2; ++md){
#pragma unroll
    for (int q4 = 0; q4 < 4; ++q4){
      ushort4 sv;
      float a0 = (md ? st.o1[4*q4+0] : st.o0[4*q4+0]) * inv;
      float a1 = (md ? st.o1[4*q4+1] : st.o0[4*q4+1]) * inv;
      float a2 = (md ? st.o1[4*q4+2] : st.o0[4*q4+2]) * inv;
      float a3 = (md ? st.o1[4*q4+3] : st.o0[4*q4+3]) * inv;
      sv.x = f2bf(a0); sv.y = f2bf(a1); sv.z = f2bf(a2); sv.w = f2bf(a3);
      *reinterpret_cast<ushort4*>(&Op[md*32 + 8*q4 + 4*hi]) = sv;
    }
  }
}

__global__ __launch_bounds__(256, 2) void k_attn2(const u16* __restrict__ Q, const u16* __restrict__ Kg,
                                                  const u16* __restrict__ VT, u16* __restrict__ O){
  const int tid = threadIdx.x, lane = tid & 63, w = tid >> 6;
  const int q32 = lane & 31, hi = lane >> 5;
  const int task = blockIdx.x * 4 + w;          // 2048 wave-tasks
  const int pr = task & 31, h = (task >> 5) & 31, b = task >> 10;
  const int kvh = h >> 2;
  const u16* Qp = Q  + ((size_t)(b*NHQ  + h  ))*NL*NHD;
  const u16* Kp = Kg + ((size_t)(b*NHKV + kvh))*NL*NHD;
  const u16* Vp = VT + ((size_t)(b*NHKV + kvh))*NHD*NL;

  AttnStream sa, sb;
  sa.qrow = (pr)      * 32 + q32;
  sb.qrow = (63 - pr) * 32 + q32;
  sa.o0 = {}; sa.o1 = {}; sa.mrun = -1e30f; sa.lsum = 0.0f;
  sb.o0 = {}; sb.o1 = {}; sb.mrun = -1e30f; sb.lsum = 0.0f;
#pragma unroll
  for (int ks = 0; ks < 4; ++ks){
    sa.qf[ks] = *reinterpret_cast<const bf16x8*>(&Qp[(size_t)sa.qrow*NHD + ks*16 + hi*8]);
    sb.qf[ks] = *reinterpret_cast<const bf16x8*>(&Qp[(size_t)sb.qrow*NHD + ks*16 + hi*8]);
  }
  const int ntA = (pr*32 + 95) >> 6;            // trip counts (A < B always)
  const int ntB = ((63-pr)*32 + 95) >> 6;

  bf16x8 kf[8], vf[8];
  // phase 1: fused, unmasked
  for (int jt = 0; jt < ntA - 1; ++jt){
    const int kvb = jt << 6;
    load_kfrag(kf, Kp, kvb, q32, hi);
    load_vfrag(vf, Vp, kvb, q32, hi);
    tile_stream<false>(sa, kf, vf, kvb, hi);
    tile_stream<false>(sb, kf, vf, kvb, hi);
  }
  // peeled: A's edge (masked) + B same tile (unmasked)
  {
    const int kvb = (ntA - 1) << 6;
    load_kfrag(kf, Kp, kvb, q32, hi);
    load_vfrag(vf, Vp, kvb, q32, hi);
    tile_stream<true >(sa, kf, vf, kvb, hi);
    tile_stream<false>(sb, kf, vf, kvb, hi);
  }
  store_stream(sa, O, b, h, hi);
  // phase 2: B alone
  for (int jt = ntA; jt < ntB - 1; ++jt){
    const int kvb = jt << 6;
    load_kfrag(kf, Kp, kvb, q32, hi);
    load_vfrag(vf, Vp, kvb, q32, hi);
    tile_stream<false>(sb, kf, vf, kvb, hi);
  }
  {
    const int kvb = (ntB - 1) << 6;
    load_kfrag(kf, Kp, kvb, q32, hi);
    load_vfrag(vf, Vp, kvb, q32, hi);
    tile_stream<true>(sb, kf, vf, kvb, hi);
  }
  store_stream(sb, O, b, h, hi);
}

extern "C" void kernel_launch(void* const* d_in, const int* in_sizes, int n_in,
                              void* d_out, int out_size, void* d_ws, size_t ws_size,
                              hipStream_t stream){
  (void)in_sizes; (void)n_in; (void)out_size; (void)ws_size;
  const float* x   = (const float*)d_in[0];
  const int*   pos = (const int*)  d_in[1];
  const float* wq  = (const float*)d_in[2];
  const float* wk  = (const float*)d_in[3];
  const float* wv  = (const float*)d_in[4];
  const float* wo  = (const float*)d_in[5];

  char* ws = (char*)d_ws;
  size_t off = 0;
  auto alloc = [&](size_t bytes) -> void* {
    void* p = ws + off;
    off += (bytes + 255) & ~(size_t)255;
    return p;
  };
  const size_t n_x   = (size_t)NB*NL*ND;
  const size_t n_wq  = (size_t)ND*ND;
  const size_t n_wkv = (size_t)NHKV*NHD*ND;

  u16* xb    = (u16*)alloc(n_x*2);                       // reused as attn output O
  u16* wqkvb = (u16*)alloc((size_t)NQKV*ND*2);
  u16* wob   = (u16*)alloc(n_wq*2);
  u16* qkv   = (u16*)alloc((size_t)NB*NL*NQKV*2);
  u16* Qb    = (u16*)alloc((size_t)NB*NHQ*NL*NHD*2);
  u16* Kb    = (u16*)alloc((size_t)NB*NHKV*NL*NHD*2);
  u16* Vb    = (u16*)alloc((size_t)NB*NHKV*NL*NHD*2);
  u16* VTb   = (u16*)alloc((size_t)NB*NHKV*NHD*NL*2);
  float* cosT= (float*)alloc((size_t)NL*32*4);
  float* sinT= (float*)alloc((size_t)NL*32*4);

  k_cvt<<<(int)(n_x/4/256),   256, 0, stream>>>(x,  xb, (int)(n_x/4));
  k_cvt<<<(int)(n_wq/4/256),  256, 0, stream>>>(wq, wqkvb, (int)(n_wq/4));
  k_cvt<<<(int)(n_wkv/4/256), 256, 0, stream>>>(wk, wqkvb + n_wq, (int)(n_wkv/4));
  k_cvt<<<(int)(n_wkv/4/256), 256, 0, stream>>>(wv, wqkvb + n_wq + n_wkv, (int)(n_wkv/4));
  k_cvt<<<(int)(n_wq/4/256),  256, 0, stream>>>(wo, wob, (int)(n_wq/4));
  k_rope_tab<<<(NL*32)/256, 256, 0, stream>>>(pos, cosT, sinT);

  k_gemm_nt<0><<<dim3(NQKV/128, (NB*NL)/128), 256, 0, stream>>>(xb, wqkvb, qkv, NB*NL, NQKV, ND);
  k_rope_scatter<<<NB*NL, 256, 0, stream>>>(qkv, cosT, sinT, Qb, Kb, Vb);
  k_transpose<<<NB*NHKV*(NL/64), 256, 0, stream>>>(Vb, VTb);
  k_attn2<<<512, 256, 0, stream>>>(Qb, Kb, VTb, xb);
  k_gemm_nt<1><<<dim3(ND/128, (NB*NL)/128), 256, 0, stream>>>(xb, wob, d_out, NB*NL, ND, ND);
}